// Round 1
// baseline (237.856 us; speedup 1.0000x reference)
//
#include <hip/hip_runtime.h>
#include <hip/hip_bf16.h>

// FLoss: mean over i of (1 - output[i, target[i]])^2
// output: [N,2] float32, target: [N] int32 (0/1), result: scalar float32.
// Pure streaming reduction -> HBM-bound. 192 MiB read => ~32 us floor @6.3TB/s.

#define N_TOTAL 16777216
#define BLOCK 256
#define GRID 4096

__global__ __launch_bounds__(BLOCK) void floss_kernel(
    const float4* __restrict__ out4,   // 2 rows per float4
    const int4*  __restrict__ tgt4,    // 4 rows per int4
    float* __restrict__ result,
    int n4)                            // N/4
{
    float acc = 0.0f;
    const int stride = gridDim.x * blockDim.x;
    for (int i = blockIdx.x * blockDim.x + threadIdx.x; i < n4; i += stride) {
        float4 a = out4[2 * i];        // rows 4i, 4i+1: (r0.c0, r0.c1, r1.c0, r1.c1)
        float4 b = out4[2 * i + 1];    // rows 4i+2, 4i+3
        int4   t = tgt4[i];
        float x0 = t.x ? a.y : a.x;
        float x1 = t.y ? a.w : a.z;
        float x2 = t.z ? b.y : b.x;
        float x3 = t.w ? b.w : b.z;
        float d0 = 1.0f - x0, d1 = 1.0f - x1, d2 = 1.0f - x2, d3 = 1.0f - x3;
        acc += d0 * d0 + d1 * d1 + d2 * d2 + d3 * d3;
    }

    // wave-64 butterfly reduce
    #pragma unroll
    for (int off = 32; off > 0; off >>= 1)
        acc += __shfl_down(acc, off, 64);

    __shared__ float smem[BLOCK / 64];
    const int lane = threadIdx.x & 63;
    const int wave = threadIdx.x >> 6;
    if (lane == 0) smem[wave] = acc;
    __syncthreads();

    if (threadIdx.x == 0) {
        float s = 0.0f;
        #pragma unroll
        for (int w = 0; w < BLOCK / 64; ++w) s += smem[w];
        // scale per-block so the final atomic sum IS the mean
        atomicAdd(result, s * (1.0f / (float)N_TOTAL));
    }
}

extern "C" void kernel_launch(void* const* d_in, const int* in_sizes, int n_in,
                              void* d_out, int out_size, void* d_ws, size_t ws_size,
                              hipStream_t stream) {
    const float4* out4 = (const float4*)d_in[0];
    const int4*   tgt4 = (const int4*)d_in[1];
    float* result = (float*)d_out;

    // d_out is poisoned to 0xAA before every timed launch -> zero it on-stream.
    hipMemsetAsync(d_out, 0, sizeof(float), stream);

    const int n4 = N_TOTAL / 4;
    floss_kernel<<<GRID, BLOCK, 0, stream>>>(out4, tgt4, result, n4);
}

// Round 2
// 231.792 us; speedup vs baseline: 1.0262x; 1.0262x over previous
//
#include <hip/hip_runtime.h>
#include <hip/hip_bf16.h>

// FLoss: mean over i of (1 - output[i, target[i]])^2
// output: [N,2] float32, target: [N] int32 (0/1), result: scalar float32.
// HBM/LLC-streaming reduction. R1 was latency-bound (VALUBusy 3.8%, 82us):
// only 3 loads in flight per wave. R2: fully-unrolled single pass, 12
// independent 16B loads per thread issued before any dependent use.

#define N_TOTAL 16777216
#define BLOCK 256
#define UNITS_PER_THREAD 4                      // 1 unit = 4 rows = 2 float4 + 1 int4
#define UNITS_PER_BLOCK (BLOCK * UNITS_PER_THREAD)   // 1024 units = 4096 rows
#define GRID (N_TOTAL / (UNITS_PER_BLOCK * 4))       // 4096 blocks, exactly one pass

__global__ __launch_bounds__(BLOCK) void floss_kernel(
    const float4* __restrict__ out4,   // 2 rows per float4
    const int4*  __restrict__ tgt4,    // 4 rows per int4
    float* __restrict__ result)
{
    const int t = threadIdx.x;
    const int ubase = blockIdx.x * UNITS_PER_BLOCK;

    float4 a[UNITS_PER_THREAD];   // rows 4u .. 4u+1
    float4 b[UNITS_PER_THREAD];   // rows 4u+2 .. 4u+3
    int4   tg[UNITS_PER_THREAD];

    // Issue all 12 loads with no dependent compute in between -> max MLP.
    #pragma unroll
    for (int j = 0; j < UNITS_PER_THREAD; ++j) {
        const int u = ubase + j * BLOCK + t;
        a[j]  = out4[2 * u];
        b[j]  = out4[2 * u + 1];
        tg[j] = tgt4[u];
    }

    float acc = 0.0f;
    #pragma unroll
    for (int j = 0; j < UNITS_PER_THREAD; ++j) {
        float x0 = tg[j].x ? a[j].y : a[j].x;
        float x1 = tg[j].y ? a[j].w : a[j].z;
        float x2 = tg[j].z ? b[j].y : b[j].x;
        float x3 = tg[j].w ? b[j].w : b[j].z;
        float d0 = 1.0f - x0, d1 = 1.0f - x1, d2 = 1.0f - x2, d3 = 1.0f - x3;
        acc += d0 * d0 + d1 * d1 + d2 * d2 + d3 * d3;
    }

    // wave-64 butterfly reduce
    #pragma unroll
    for (int off = 32; off > 0; off >>= 1)
        acc += __shfl_down(acc, off, 64);

    __shared__ float smem[BLOCK / 64];
    const int lane = threadIdx.x & 63;
    const int wave = threadIdx.x >> 6;
    if (lane == 0) smem[wave] = acc;
    __syncthreads();

    if (threadIdx.x == 0) {
        float s = 0.0f;
        #pragma unroll
        for (int w = 0; w < BLOCK / 64; ++w) s += smem[w];
        // scale per-block so the final atomic sum IS the mean
        atomicAdd(result, s * (1.0f / (float)N_TOTAL));
    }
}

extern "C" void kernel_launch(void* const* d_in, const int* in_sizes, int n_in,
                              void* d_out, int out_size, void* d_ws, size_t ws_size,
                              hipStream_t stream) {
    const float4* out4 = (const float4*)d_in[0];
    const int4*   tgt4 = (const int4*)d_in[1];
    float* result = (float*)d_out;

    // d_out is poisoned to 0xAA before every timed launch -> zero it on-stream.
    hipMemsetAsync(d_out, 0, sizeof(float), stream);

    floss_kernel<<<GRID, BLOCK, 0, stream>>>(out4, tgt4, result);
}

// Round 3
// 231.186 us; speedup vs baseline: 1.0289x; 1.0026x over previous
//
#include <hip/hip_runtime.h>
#include <hip/hip_bf16.h>

// FLoss: mean over i of (1 - output[i, target[i]])^2
// output: [N,2] float32, target: [N] int32 (0/1), result: scalar float32.
//
// R1 (82us): latency-bound, 3 loads in flight. R2 (~76us): 12 loads in
// flight but every out4 instruction was 32B-strided -> 50% dense -> 2x
// cache-line requests per instruction, effective rate capped ~2.6 TB/s.
// R3: unit = one float4 (rows 2p,2p+1) + one int2 (targets 2p,2p+1) at the
// SAME index p -> every load instruction is fully lane-contiguous.

#define N_TOTAL 16777216
#define BLOCK 256
#define F4_PER_THREAD 8
#define F4_PER_BLOCK (BLOCK * F4_PER_THREAD)          // 2048 float4 = 4096 rows
#define N_F4 (N_TOTAL / 2)                            // 8388608 float4 in output
#define GRID (N_F4 / F4_PER_BLOCK)                    // 4096 blocks, one pass

__global__ __launch_bounds__(BLOCK) void floss_kernel(
    const float4* __restrict__ out4,   // float4 p = rows 2p,2p+1 (cols interleaved)
    const int2*  __restrict__ tgt2,    // int2  p = targets 2p,2p+1
    float* __restrict__ result)
{
    const int t = threadIdx.x;
    const int pbase = blockIdx.x * F4_PER_BLOCK;

    float4 f[F4_PER_THREAD];
    int2   g[F4_PER_THREAD];

    // 16 independent, fully-coalesced loads before any dependent use.
    #pragma unroll
    for (int j = 0; j < F4_PER_THREAD; ++j) {
        const int p = pbase + j * BLOCK + t;
        f[j] = out4[p];
        g[j] = tgt2[p];
    }

    float acc = 0.0f;
    #pragma unroll
    for (int j = 0; j < F4_PER_THREAD; ++j) {
        float x0 = g[j].x ? f[j].y : f[j].x;
        float x1 = g[j].y ? f[j].w : f[j].z;
        float d0 = 1.0f - x0, d1 = 1.0f - x1;
        acc += d0 * d0 + d1 * d1;
    }

    // wave-64 butterfly reduce
    #pragma unroll
    for (int off = 32; off > 0; off >>= 1)
        acc += __shfl_down(acc, off, 64);

    __shared__ float smem[BLOCK / 64];
    const int lane = threadIdx.x & 63;
    const int wave = threadIdx.x >> 6;
    if (lane == 0) smem[wave] = acc;
    __syncthreads();

    if (threadIdx.x == 0) {
        float s = 0.0f;
        #pragma unroll
        for (int w = 0; w < BLOCK / 64; ++w) s += smem[w];
        // scale per-block so the final atomic sum IS the mean
        atomicAdd(result, s * (1.0f / (float)N_TOTAL));
    }
}

extern "C" void kernel_launch(void* const* d_in, const int* in_sizes, int n_in,
                              void* d_out, int out_size, void* d_ws, size_t ws_size,
                              hipStream_t stream) {
    const float4* out4 = (const float4*)d_in[0];
    const int2*   tgt2 = (const int2*)d_in[1];
    float* result = (float*)d_out;

    // d_out is poisoned to 0xAA before every timed launch -> zero it on-stream.
    hipMemsetAsync(d_out, 0, sizeof(float), stream);

    floss_kernel<<<GRID, BLOCK, 0, stream>>>(out4, tgt2, result);
}

// Round 4
// 229.636 us; speedup vs baseline: 1.0358x; 1.0067x over previous
//
#include <hip/hip_runtime.h>
#include <hip/hip_bf16.h>

// FLoss: mean over i of (1 - output[i, target[i]])^2
// output: [N,2] float32, target: [N] int32 (0/1), result: scalar float32.
//
// History: R1 82us (latency theory), R2 ~76us (MLP 12 loads), R3 ~76us
// (fully coalesced) -- coalescing+MLP bought ~nothing. Kernel pinned at
// ~76us with all memory tiers <25% utilized => the serializer is the 4096
// same-address device-scope atomicAdds (76us*2.4GHz/4096 ~= 44 cyc/atomic,
// cross-XCD RMW to one coherence point).
// R4: two-stage reduce. K1: blocks store disjoint partials to d_ws (no
// atomics). K2: one block reduces 4096 partials -> mean.

#define N_TOTAL 16777216
#define BLOCK 256
#define F4_PER_THREAD 8
#define F4_PER_BLOCK (BLOCK * F4_PER_THREAD)          // 2048 float4 = 4096 rows
#define N_F4 (N_TOTAL / 2)                            // 8388608 float4 in output
#define GRID (N_F4 / F4_PER_BLOCK)                    // 4096 blocks, one pass

__global__ __launch_bounds__(BLOCK) void floss_partial_kernel(
    const float4* __restrict__ out4,   // float4 p = rows 2p,2p+1 (cols interleaved)
    const int2*  __restrict__ tgt2,    // int2  p = targets 2p,2p+1
    float* __restrict__ partials)      // [GRID]
{
    const int t = threadIdx.x;
    const int pbase = blockIdx.x * F4_PER_BLOCK;

    float4 f[F4_PER_THREAD];
    int2   g[F4_PER_THREAD];

    // 16 independent, fully-coalesced loads before any dependent use.
    #pragma unroll
    for (int j = 0; j < F4_PER_THREAD; ++j) {
        const int p = pbase + j * BLOCK + t;
        f[j] = out4[p];
        g[j] = tgt2[p];
    }

    float acc = 0.0f;
    #pragma unroll
    for (int j = 0; j < F4_PER_THREAD; ++j) {
        float x0 = g[j].x ? f[j].y : f[j].x;
        float x1 = g[j].y ? f[j].w : f[j].z;
        float d0 = 1.0f - x0, d1 = 1.0f - x1;
        acc += d0 * d0 + d1 * d1;
    }

    // wave-64 butterfly reduce
    #pragma unroll
    for (int off = 32; off > 0; off >>= 1)
        acc += __shfl_down(acc, off, 64);

    __shared__ float smem[BLOCK / 64];
    const int lane = threadIdx.x & 63;
    const int wave = threadIdx.x >> 6;
    if (lane == 0) smem[wave] = acc;
    __syncthreads();

    if (threadIdx.x == 0) {
        float s = 0.0f;
        #pragma unroll
        for (int w = 0; w < BLOCK / 64; ++w) s += smem[w];
        partials[blockIdx.x] = s;      // plain store, disjoint addresses
    }
}

__global__ __launch_bounds__(BLOCK) void floss_final_kernel(
    const float4* __restrict__ partials4,   // GRID/4 = 1024 float4
    float* __restrict__ result)
{
    const int t = threadIdx.x;
    float acc = 0.0f;
    #pragma unroll
    for (int j = 0; j < GRID / 4 / BLOCK; ++j) {     // 4 float4 per thread
        float4 p = partials4[j * BLOCK + t];
        acc += p.x + p.y + p.z + p.w;
    }

    #pragma unroll
    for (int off = 32; off > 0; off >>= 1)
        acc += __shfl_down(acc, off, 64);

    __shared__ float smem[BLOCK / 64];
    const int lane = threadIdx.x & 63;
    const int wave = threadIdx.x >> 6;
    if (lane == 0) smem[wave] = acc;
    __syncthreads();

    if (threadIdx.x == 0) {
        float s = 0.0f;
        #pragma unroll
        for (int w = 0; w < BLOCK / 64; ++w) s += smem[w];
        *result = s * (1.0f / (float)N_TOTAL);   // unconditional write
    }
}

extern "C" void kernel_launch(void* const* d_in, const int* in_sizes, int n_in,
                              void* d_out, int out_size, void* d_ws, size_t ws_size,
                              hipStream_t stream) {
    const float4* out4 = (const float4*)d_in[0];
    const int2*   tgt2 = (const int2*)d_in[1];
    float* partials = (float*)d_ws;          // 4096 floats = 16 KiB of scratch
    float* result = (float*)d_out;

    floss_partial_kernel<<<GRID, BLOCK, 0, stream>>>(out4, tgt2, partials);
    floss_final_kernel<<<1, BLOCK, 0, stream>>>((const float4*)partials, result);
}